// Round 2
// baseline (915.284 us; speedup 1.0000x reference)
//
#include <hip/hip_runtime.h>
#include <math.h>

// Problem constants (B=4, H=16, S=4096, D=64, m=256)
#define DNORM   0.35355339059327376f   // sqrt(softmax_temp) = (1/8)^0.5
#define DIAG_F  0.0625f                // 0.5 * softmax_temp = 0.5/8
#define HLM     2.772588722239781f     // log(256)/2
#define ROWS_TOTAL   262144            // B*H*S
#define FEAT_ELEMS   67108864          // B*H*S*256

// LDS projection tile: 128 rows x 16 float4 chunks (32 KiB), chunk-XOR swizzled
// so per-wave reads pd[l][c^(l&15)] land on 16 distinct addresses spread evenly
// over the 8 four-bank groups (2-way aliasing only = free on CDNA4).
__device__ __forceinline__ void load_proj(const float* __restrict__ proj,
                                          float4 (*pd)[16], int tid) {
    const float4* p4 = reinterpret_cast<const float4*>(proj);
#pragma unroll
    for (int i = 0; i < 8; ++i) {
        int idx = tid + i * 256;          // 0..2047
        int j = idx >> 4;                 // proj row 0..127
        int c = idx & 15;                 // chunk 0..15
        float4 v = p4[idx];
        v.x *= DNORM; v.y *= DNORM; v.z *= DNORM; v.w *= DNORM;
        pd[j][c ^ (j & 15)] = v;
    }
}

// One wave computes 8 data rows against its 2 proj rows (lane l owns proj rows
// l and l+64). Each proj fragment read from LDS is reused across 8 rows, so
// LDS traffic is 8x lower than FMA traffic. Row data arrives as wave-uniform
// float4 broadcasts (L1-served; the diag pass pre-warms the lines coalesced).
__device__ __forceinline__ void proc8(const float* __restrict__ data, size_t row0,
                                      const float4 (*pd)[16], int l,
                                      float x0[8], float x1[8], float diag[8]) {
#pragma unroll
    for (int i = 0; i < 8; ++i) {
        float v = data[(row0 + i) * 64 + l];   // coalesced, warms L1
        float dd = v * v;
#pragma unroll
        for (int s = 32; s; s >>= 1) dd += __shfl_xor(dd, s, 64);
        diag[i] = dd * DIAG_F;
        x0[i] = 0.f; x1[i] = 0.f;
    }
    const float4* r4 = reinterpret_cast<const float4*>(data + row0 * 64);
    int lx = l & 15;
#pragma unroll
    for (int c = 0; c < 16; ++c) {
        float4 p0 = pd[l][c ^ lx];
        float4 p1 = pd[l + 64][c ^ lx];
#pragma unroll
        for (int i = 0; i < 8; ++i) {
            float4 r = r4[i * 16 + c];         // wave-uniform broadcast
            x0[i] = fmaf(r.w, p0.w, fmaf(r.z, p0.z, fmaf(r.y, p0.y, fmaf(r.x, p0.x, x0[i]))));
            x1[i] = fmaf(r.w, p1.w, fmaf(r.z, p1.z, fmaf(r.y, p1.y, fmaf(r.x, p1.x, x1[i]))));
        }
    }
}

__device__ __forceinline__ float wave_max(float m) {
#pragma unroll
    for (int s = 32; s; s >>= 1) m = fmaxf(m, __shfl_xor(m, s, 64));
    return m;
}

// Pass 1 for k: per-block max of (max_j |x_j| - diag - hlm) over 64 rows.
// diag is wave-uniform, so per-lane candidates fold across rows first and a
// single butterfly at the end suffices.
__global__ __launch_bounds__(256) void kmax_kernel(const float* __restrict__ k,
                                                   const float* __restrict__ proj,
                                                   float* __restrict__ partials) {
    __shared__ float4 pd[128][16];
    __shared__ float red[4];
    int tid = threadIdx.x;
    load_proj(proj, pd, tid);
    __syncthreads();
    int wave = tid >> 6, l = tid & 63;
    size_t row0 = (size_t)blockIdx.x * 64 + wave * 16;
    float cand = -INFINITY;
#pragma unroll
    for (int g = 0; g < 2; ++g) {
        float x0[8], x1[8], diag[8];
        proc8(k, row0 + g * 8, pd, l, x0, x1, diag);
#pragma unroll
        for (int i = 0; i < 8; ++i)
            cand = fmaxf(cand, fmaxf(fabsf(x0[i]), fabsf(x1[i])) - diag[i]);
    }
    float wmax = wave_max(cand) - HLM;
    if (l == 0) red[wave] = wmax;
    __syncthreads();
    if (tid == 0)
        partials[blockIdx.x] =
            fmaxf(fmaxf(red[0], red[1]), fmaxf(red[2], red[3]));
}

// Reduce 64 block-partials per (b,h) -> k_log_scale[64]
__global__ void kmax_reduce(const float* __restrict__ partials,
                            float* __restrict__ kls) {
    int bh = threadIdx.x;  // 0..63
    float m = -INFINITY;
    for (int i = 0; i < 64; ++i) m = fmaxf(m, partials[bh * 64 + i]);
    kls[bh] = m;
}

// q features + per-row log scale
__global__ __launch_bounds__(256) void qfeat_kernel(const float* __restrict__ q,
                                                    const float* __restrict__ proj,
                                                    float* __restrict__ qf,
                                                    float* __restrict__ qls) {
    __shared__ float4 pd[128][16];
    int tid = threadIdx.x;
    load_proj(proj, pd, tid);
    __syncthreads();
    int wave = tid >> 6, l = tid & 63;
    size_t row0 = (size_t)blockIdx.x * 64 + wave * 16;
#pragma unroll
    for (int g = 0; g < 2; ++g) {
        float x0[8], x1[8], diag[8];
        size_t r0 = row0 + g * 8;
        proc8(q, r0, pd, l, x0, x1, diag);
#pragma unroll
        for (int i = 0; i < 8; ++i) {
            float amax = wave_max(fmaxf(fabsf(x0[i]), fabsf(x1[i])));
            float e0 = __expf(x0[i] - amax);
            float e1 = __expf(x1[i] - amax);
            float e2 = __expf(-x0[i] - amax);
            float e3 = __expf(-x1[i] - amax);
            float* o = qf + (r0 + i) * 256 + l;
            o[0] = e0; o[64] = e1; o[128] = e2; o[192] = e3;
            if (l == 0) qls[r0 + i] = amax - diag[i] - HLM;
        }
    }
}

// k features using the global per-(b,h) log scale
__global__ __launch_bounds__(256) void kfeat_kernel(const float* __restrict__ k,
                                                    const float* __restrict__ proj,
                                                    float* __restrict__ kf,
                                                    const float* __restrict__ kls) {
    __shared__ float4 pd[128][16];
    int tid = threadIdx.x;
    load_proj(proj, pd, tid);
    __syncthreads();
    float gls = kls[blockIdx.x >> 6];  // 64 blocks per (b,h)
    int wave = tid >> 6, l = tid & 63;
    size_t row0 = (size_t)blockIdx.x * 64 + wave * 16;
#pragma unroll
    for (int g = 0; g < 2; ++g) {
        float x0[8], x1[8], diag[8];
        size_t r0 = row0 + g * 8;
        proc8(k, r0, pd, l, x0, x1, diag);
#pragma unroll
        for (int i = 0; i < 8; ++i) {
            float off = diag[i] + HLM + gls;
            float e0 = __expf(x0[i] - off);
            float e1 = __expf(x1[i] - off);
            float e2 = __expf(-x0[i] - off);
            float e3 = __expf(-x1[i] - off);
            float* o = kf + (r0 + i) * 256 + l;
            o[0] = e0; o[64] = e1; o[128] = e2; o[192] = e3;
        }
    }
}

extern "C" void kernel_launch(void* const* d_in, const int* in_sizes, int n_in,
                              void* d_out, int out_size, void* d_ws, size_t ws_size,
                              hipStream_t stream) {
    const float* q    = (const float*)d_in[0];
    const float* k    = (const float*)d_in[1];
    const float* proj = (const float*)d_in[2];

    float* out = (float*)d_out;
    float* qf  = out;                                       // (B,H,S,256)
    float* qls = out + (size_t)FEAT_ELEMS;                  // (B,H,S,1)
    float* kf  = out + (size_t)FEAT_ELEMS + ROWS_TOTAL;     // (B,H,S,256)
    float* kls = out + 2 * (size_t)FEAT_ELEMS + ROWS_TOTAL; // (B,H,1,1)

    float* partials = (ws_size >= 4096 * sizeof(float)) ? (float*)d_ws : kf;

    const int blocks = ROWS_TOTAL / 64;  // 4096
    kmax_kernel <<<blocks, 256, 0, stream>>>(k, proj, partials);
    kmax_reduce <<<1, 64, 0, stream>>>(partials, kls);
    qfeat_kernel<<<blocks, 256, 0, stream>>>(q, proj, qf, qls);
    kfeat_kernel<<<blocks, 256, 0, stream>>>(k, proj, kf, kls);
}

// Round 3
// 180.033 us; speedup vs baseline: 5.0840x; 5.0840x over previous
//
#include <hip/hip_runtime.h>
#include <math.h>

// Problem constants (B=4, H=16, S=4096, D=64, m=256)
#define DNORM   0.35355339059327376f   // sqrt(softmax_temp) = (1/8)^0.5
#define DIAG_F  0.0625f                // 0.5 * softmax_temp
#define HLM     2.772588722239781f     // log(256)/2
#define ROWS_TOTAL   262144            // B*H*S
#define FEAT_ELEMS   67108864          // B*H*S*256
#define ROWS_PER_BLK 128
#define NBLOCKS      2048              // ROWS_TOTAL / 128
#define BLKS_PER_BH  32                // 4096 / 128

using bf16x8 = __attribute__((ext_vector_type(8))) short;
using f32x4  = __attribute__((ext_vector_type(4))) float;

__device__ __forceinline__ unsigned short f2bf(float f) {
    unsigned int u = __builtin_bit_cast(unsigned int, f);
    u = (u + 0x7FFFu + ((u >> 16) & 1u)) >> 16;   // RNE
    return (unsigned short)u;
}

// ---------------------------------------------------------------------------
// Prep: pack proj (128x64 fp32) * DNORM into MFMA B-fragment order in d_ws.
// Slot s = (jt<<7)|(h<<6)|lane ; lane: n=lane&15 (j within tile), dg=lane>>4;
// 8 bf16 = proj[jt*16+n][h*32+dg*8 .. +7]. 1024 slots x 16B = 16 KB.
// ---------------------------------------------------------------------------
__global__ void prep_proj(const float* __restrict__ proj,
                          unsigned short* __restrict__ pb) {
    int t = threadIdx.x;  // 256
#pragma unroll
    for (int i = 0; i < 4; ++i) {
        int s  = t + i * 256;
        int jt = s >> 7, h = (s >> 6) & 1, l = s & 63;
        int n = l & 15, dg = l >> 4;
        const float* p = proj + (jt * 16 + n) * 64 + h * 32 + dg * 8;
        unsigned int w0 = (unsigned int)f2bf(p[0] * DNORM) | ((unsigned int)f2bf(p[1] * DNORM) << 16);
        unsigned int w1 = (unsigned int)f2bf(p[2] * DNORM) | ((unsigned int)f2bf(p[3] * DNORM) << 16);
        unsigned int w2 = (unsigned int)f2bf(p[4] * DNORM) | ((unsigned int)f2bf(p[5] * DNORM) << 16);
        unsigned int w3 = (unsigned int)f2bf(p[6] * DNORM) | ((unsigned int)f2bf(p[7] * DNORM) << 16);
        uint4 o = make_uint4(w0, w1, w2, w3);
        *reinterpret_cast<uint4*>(pb + (size_t)s * 8) = o;
    }
}

// ---------------------------------------------------------------------------
// Shared tile compute: stage 128 data rows -> bf16 A-fragments + diag, load
// packed B, run 32 MFMA per wave. acc[r][jt] holds the 16x16 tile
// (rowtile = wave*2+r, coltile = jt); C layout: col=lane&15, row=(lane>>4)*4+reg.
// ---------------------------------------------------------------------------
struct TileCtx {
    f32x4 acc[2][8];
    int l, w;           // lane, wave
};

__device__ __forceinline__ void compute_tiles(
        const float* __restrict__ data, const unsigned short* __restrict__ pb,
        unsigned short (*As)[2][64][8], unsigned short (*Bs)[2][64][8],
        float* diag_s, TileCtx& ctx) {
    int t = threadIdx.x;
    // B: 16 KB coalesced copy (L2-hot after first block)
    const uint4* src = reinterpret_cast<const uint4*>(pb);
    uint4* dstB = reinterpret_cast<uint4*>(&Bs[0][0][0][0]);
#pragma unroll
    for (int i = 0; i < 4; ++i) dstB[t + i * 256] = src[t + i * 256];

    // A: 128 rows x 64 fp32, coalesced float4; convert to bf16 fragments + diag
    const float4* g = reinterpret_cast<const float4*>(data + (size_t)blockIdx.x * ROWS_PER_BLK * 64);
#pragma unroll
    for (int i = 0; i < 8; ++i) {
        int idx = t + i * 256;
        int c = t & 15;            // chunk within row
        int m = t >> 4;            // row & 15
        int row = m + 16 * i;      // block-local row (rt = i)
        float4 v = g[idx];
        float ss = v.x * v.x + v.y * v.y + v.z * v.z + v.w * v.w;
        ss += __shfl_xor(ss, 1, 64);
        ss += __shfl_xor(ss, 2, 64);
        ss += __shfl_xor(ss, 4, 64);
        ss += __shfl_xor(ss, 8, 64);
        if (c == 0) diag_s[row] = ss * DIAG_F;
        int h = c >> 3, dg = (c >> 1) & 3, half = c & 1;
        uint2 wv;
        wv.x = (unsigned int)f2bf(v.x) | ((unsigned int)f2bf(v.y) << 16);
        wv.y = (unsigned int)f2bf(v.z) | ((unsigned int)f2bf(v.w) << 16);
        *reinterpret_cast<uint2*>(&As[i][h][dg * 16 + m][half * 4]) = wv;
    }
    __syncthreads();

    int l = t & 63, w = t >> 6;
    ctx.l = l; ctx.w = w;
    bf16x8 fa[2][2];
#pragma unroll
    for (int r = 0; r < 2; ++r)
#pragma unroll
        for (int h = 0; h < 2; ++h)
            fa[r][h] = *reinterpret_cast<bf16x8*>(&As[w * 2 + r][h][l][0]);
#pragma unroll
    for (int r = 0; r < 2; ++r)
#pragma unroll
        for (int jt = 0; jt < 8; ++jt)
            ctx.acc[r][jt] = f32x4{0.f, 0.f, 0.f, 0.f};
#pragma unroll
    for (int jt = 0; jt < 8; ++jt) {
        bf16x8 fb0 = *reinterpret_cast<bf16x8*>(&Bs[jt][0][l][0]);
        bf16x8 fb1 = *reinterpret_cast<bf16x8*>(&Bs[jt][1][l][0]);
#pragma unroll
        for (int r = 0; r < 2; ++r) {
            ctx.acc[r][jt] = __builtin_amdgcn_mfma_f32_16x16x32_bf16(fa[r][0], fb0, ctx.acc[r][jt], 0, 0, 0);
            ctx.acc[r][jt] = __builtin_amdgcn_mfma_f32_16x16x32_bf16(fa[r][1], fb1, ctx.acc[r][jt], 0, 0, 0);
        }
    }
}

// ---------------------------------------------------------------------------
// q features: per-row amax, exp, per-row log scale
// ---------------------------------------------------------------------------
__global__ __launch_bounds__(256) void qfeat_kernel(
        const float* __restrict__ q, const unsigned short* __restrict__ pb,
        float* __restrict__ qf, float* __restrict__ qls) {
    __shared__ unsigned short As[8][2][64][8];
    __shared__ unsigned short Bs[8][2][64][8];
    __shared__ float diag_s[ROWS_PER_BLK];
    TileCtx ctx;
    compute_tiles(q, pb, As, Bs, diag_s, ctx);
    int l = ctx.l, w = ctx.w;
    int n = l & 15;
#pragma unroll
    for (int r = 0; r < 2; ++r) {
        int rt = w * 2 + r;
#pragma unroll
        for (int q4 = 0; q4 < 4; ++q4) {
            int row = rt * 16 + (l >> 4) * 4 + q4;
            float mx = 0.f;  // max over concat[x,-x] = max|x|
#pragma unroll
            for (int jt = 0; jt < 8; ++jt) mx = fmaxf(mx, fabsf(ctx.acc[r][jt][q4]));
            mx = fmaxf(mx, __shfl_xor(mx, 1, 64));
            mx = fmaxf(mx, __shfl_xor(mx, 2, 64));
            mx = fmaxf(mx, __shfl_xor(mx, 4, 64));
            mx = fmaxf(mx, __shfl_xor(mx, 8, 64));
            size_t R = (size_t)blockIdx.x * ROWS_PER_BLK + row;
            float* o = qf + R * 256 + n;
#pragma unroll
            for (int jt = 0; jt < 8; ++jt) {
                float x = ctx.acc[r][jt][q4];
                o[jt * 16]       = __expf(x - mx);
                o[jt * 16 + 128] = __expf(-x - mx);
            }
            if (n == 0) qls[R] = mx - diag_s[row] - HLM;
        }
    }
}

// ---------------------------------------------------------------------------
// k max pass: per-block max of (|x| - diag) ; -HLM folded at the end
// ---------------------------------------------------------------------------
__global__ __launch_bounds__(256) void kmax_kernel(
        const float* __restrict__ k, const unsigned short* __restrict__ pb,
        float* __restrict__ partials) {
    __shared__ unsigned short As[8][2][64][8];
    __shared__ unsigned short Bs[8][2][64][8];
    __shared__ float diag_s[ROWS_PER_BLK];
    __shared__ float red[4];
    TileCtx ctx;
    compute_tiles(k, pb, As, Bs, diag_s, ctx);
    int l = ctx.l, w = ctx.w;
    float cand = -INFINITY;
#pragma unroll
    for (int r = 0; r < 2; ++r) {
        int rt = w * 2 + r;
#pragma unroll
        for (int q4 = 0; q4 < 4; ++q4) {
            int row = rt * 16 + (l >> 4) * 4 + q4;
            float mx = 0.f;
#pragma unroll
            for (int jt = 0; jt < 8; ++jt) mx = fmaxf(mx, fabsf(ctx.acc[r][jt][q4]));
            cand = fmaxf(cand, mx - diag_s[row]);
        }
    }
#pragma unroll
    for (int s = 32; s; s >>= 1) cand = fmaxf(cand, __shfl_xor(cand, s, 64));
    if (l == 0) red[w] = cand;
    __syncthreads();
    if (threadIdx.x == 0)
        partials[blockIdx.x] =
            fmaxf(fmaxf(red[0], red[1]), fmaxf(red[2], red[3])) - HLM;
}

__global__ void kmax_reduce(const float* __restrict__ partials,
                            float* __restrict__ kls) {
    int bh = threadIdx.x;  // 0..63
    float m = -INFINITY;
    for (int i = 0; i < BLKS_PER_BH; ++i)
        m = fmaxf(m, partials[bh * BLKS_PER_BH + i]);
    kls[bh] = m;
}

// ---------------------------------------------------------------------------
// k features with global per-(b,h) log scale
// ---------------------------------------------------------------------------
__global__ __launch_bounds__(256) void kfeat_kernel(
        const float* __restrict__ k, const unsigned short* __restrict__ pb,
        float* __restrict__ kf, const float* __restrict__ kls) {
    __shared__ unsigned short As[8][2][64][8];
    __shared__ unsigned short Bs[8][2][64][8];
    __shared__ float diag_s[ROWS_PER_BLK];
    TileCtx ctx;
    compute_tiles(k, pb, As, Bs, diag_s, ctx);
    float gls = kls[blockIdx.x >> 5];  // 32 blocks per (b,h)
    int l = ctx.l, w = ctx.w;
    int n = l & 15;
#pragma unroll
    for (int r = 0; r < 2; ++r) {
        int rt = w * 2 + r;
#pragma unroll
        for (int q4 = 0; q4 < 4; ++q4) {
            int row = rt * 16 + (l >> 4) * 4 + q4;
            float off = diag_s[row] + HLM + gls;
            size_t R = (size_t)blockIdx.x * ROWS_PER_BLK + row;
            float* o = kf + R * 256 + n;
#pragma unroll
            for (int jt = 0; jt < 8; ++jt) {
                float x = ctx.acc[r][jt][q4];
                o[jt * 16]       = __expf(x - off);
                o[jt * 16 + 128] = __expf(-x - off);
            }
        }
    }
}

extern "C" void kernel_launch(void* const* d_in, const int* in_sizes, int n_in,
                              void* d_out, int out_size, void* d_ws, size_t ws_size,
                              hipStream_t stream) {
    const float* q    = (const float*)d_in[0];
    const float* k    = (const float*)d_in[1];
    const float* proj = (const float*)d_in[2];

    float* out = (float*)d_out;
    float* qf  = out;                                       // (B,H,S,256)
    float* qls = out + (size_t)FEAT_ELEMS;                  // (B,H,S,1)
    float* kf  = out + (size_t)FEAT_ELEMS + ROWS_TOTAL;     // (B,H,S,256)
    float* kls = out + 2 * (size_t)FEAT_ELEMS + ROWS_TOTAL; // (B,H,1,1)

    unsigned short* pb = (unsigned short*)d_ws;             // 16 KB packed proj
    float* partials = (float*)((char*)d_ws + 16384);        // 2048 floats

    prep_proj  <<<1, 256, 0, stream>>>(proj, pb);
    kmax_kernel<<<NBLOCKS, 256, 0, stream>>>(k, pb, partials);
    kmax_reduce<<<1, 64, 0, stream>>>(partials, kls);
    qfeat_kernel<<<NBLOCKS, 256, 0, stream>>>(q, pb, qf, qls);
    kfeat_kernel<<<NBLOCKS, 256, 0, stream>>>(k, pb, kf, kls);
}

// Round 4
// 179.950 us; speedup vs baseline: 5.0863x; 1.0005x over previous
//
#include <hip/hip_runtime.h>
#include <math.h>

// Problem constants (B=4, H=16, S=4096, D=64, m=256)
#define DNORM   0.35355339059327376f   // sqrt(softmax_temp) = (1/8)^0.5
#define DIAG_F  0.0625f                // 0.5 * softmax_temp
#define HLM     2.772588722239781f     // log(256)/2
#define ROWS_TOTAL   262144            // B*H*S
#define FEAT_ELEMS   67108864          // B*H*S*256
#define ROWS_PER_BLK 128
#define NBLOCKS      2048              // ROWS_TOTAL / 128
#define BLKS_PER_BH  32                // 4096 / 128

using bf16x8 = __attribute__((ext_vector_type(8))) short;
using f32x4  = __attribute__((ext_vector_type(4))) float;

__device__ __forceinline__ unsigned short f2bf(float f) {
    unsigned int u = __builtin_bit_cast(unsigned int, f);
    u = (u + 0x7FFFu + ((u >> 16) & 1u)) >> 16;   // RNE
    return (unsigned short)u;
}

// ---------------------------------------------------------------------------
// Stage a 128x64 fp32 panel into MFMA fragment order (bf16), optionally
// scaling by DNORM (proj) and computing per-row diag (data). Fragment layout
// F[tile][h][dg*16 + m][half*4 .. +3]: tile = row>>4, m = row&15, element
// f = h*32 + dg*8 + (half*4 + e). Reads are fully coalesced float4.
// ---------------------------------------------------------------------------
template<bool SCALE, bool DIAG>
__device__ __forceinline__ void stage128(const float* __restrict__ src,
                                         unsigned short (*F)[2][64][8],
                                         float* diag_s, int t) {
    const float4* g = reinterpret_cast<const float4*>(src);
#pragma unroll
    for (int i = 0; i < 8; ++i) {
        int c = t & 15;            // chunk within row (4 floats)
        int m = t >> 4;            // row & 15 (block-relative within 256-thr)
        float4 v = g[t + i * 256];
        if (SCALE) { v.x *= DNORM; v.y *= DNORM; v.z *= DNORM; v.w *= DNORM; }
        if (DIAG) {
            float ss = v.x * v.x + v.y * v.y + v.z * v.z + v.w * v.w;
            ss += __shfl_xor(ss, 1, 64);
            ss += __shfl_xor(ss, 2, 64);
            ss += __shfl_xor(ss, 4, 64);
            ss += __shfl_xor(ss, 8, 64);
            if (c == 0) diag_s[m + 16 * i] = ss * DIAG_F;
        }
        int h = c >> 3, dg = (c >> 1) & 3, half = c & 1;
        uint2 wv;
        wv.x = (unsigned int)f2bf(v.x) | ((unsigned int)f2bf(v.y) << 16);
        wv.y = (unsigned int)f2bf(v.z) | ((unsigned int)f2bf(v.w) << 16);
        *reinterpret_cast<uint2*>(&F[i][h][dg * 16 + m][half * 4]) = wv;
    }
}

// ---------------------------------------------------------------------------
// MFMA core: 128 data rows x 128 proj rows. acc[r][jt] = 16x16 tile
// (rowtile = wave*2+r, coltile = jt). C layout: col=lane&15, row=(lane>>4)*4+reg.
// ---------------------------------------------------------------------------
struct TileCtx { f32x4 acc[2][8]; int l, w; };

__device__ __forceinline__ void mfma_tiles(unsigned short (*As)[2][64][8],
                                           unsigned short (*Bs)[2][64][8],
                                           TileCtx& ctx) {
    int t = threadIdx.x;
    int l = t & 63, w = t >> 6;
    ctx.l = l; ctx.w = w;
    bf16x8 fa[2][2];
#pragma unroll
    for (int r = 0; r < 2; ++r)
#pragma unroll
        for (int h = 0; h < 2; ++h)
            fa[r][h] = *reinterpret_cast<bf16x8*>(&As[w * 2 + r][h][l][0]);
#pragma unroll
    for (int r = 0; r < 2; ++r)
#pragma unroll
        for (int jt = 0; jt < 8; ++jt)
            ctx.acc[r][jt] = f32x4{0.f, 0.f, 0.f, 0.f};
#pragma unroll
    for (int jt = 0; jt < 8; ++jt) {
        bf16x8 fb0 = *reinterpret_cast<bf16x8*>(&Bs[jt][0][l][0]);
        bf16x8 fb1 = *reinterpret_cast<bf16x8*>(&Bs[jt][1][l][0]);
#pragma unroll
        for (int r = 0; r < 2; ++r) {
            ctx.acc[r][jt] = __builtin_amdgcn_mfma_f32_16x16x32_bf16(fa[r][0], fb0, ctx.acc[r][jt], 0, 0, 0);
            ctx.acc[r][jt] = __builtin_amdgcn_mfma_f32_16x16x32_bf16(fa[r][1], fb1, ctx.acc[r][jt], 0, 0, 0);
        }
    }
}

// ---------------------------------------------------------------------------
// k max pass: per-block max of (|x| - diag) - HLM -> partials[bid] (d_ws)
// ---------------------------------------------------------------------------
__global__ __launch_bounds__(256) void kmax_kernel(
        const float* __restrict__ k, const float* __restrict__ proj,
        float* __restrict__ partials) {
    __shared__ unsigned short As[8][2][64][8];
    __shared__ unsigned short Bs[8][2][64][8];
    __shared__ float diag_s[ROWS_PER_BLK];
    __shared__ float red[4];
    int t = threadIdx.x;
    stage128<true,  false>(proj, Bs, nullptr, t);
    stage128<false, true >(k + (size_t)blockIdx.x * ROWS_PER_BLK * 64, As, diag_s, t);
    __syncthreads();
    TileCtx ctx;
    mfma_tiles(As, Bs, ctx);
    int l = ctx.l, w = ctx.w;
    float cand = -INFINITY;
#pragma unroll
    for (int r = 0; r < 2; ++r) {
        int rt = w * 2 + r;
#pragma unroll
        for (int q4 = 0; q4 < 4; ++q4) {
            int row = rt * 16 + (l >> 4) * 4 + q4;
            float mx = 0.f;
#pragma unroll
            for (int jt = 0; jt < 8; ++jt) mx = fmaxf(mx, fabsf(ctx.acc[r][jt][q4]));
            cand = fmaxf(cand, mx - diag_s[row]);
        }
    }
#pragma unroll
    for (int s = 32; s; s >>= 1) cand = fmaxf(cand, __shfl_xor(cand, s, 64));
    if (l == 0) red[w] = cand;
    __syncthreads();
    if (t == 0)
        partials[blockIdx.x] =
            fmaxf(fmaxf(red[0], red[1]), fmaxf(red[2], red[3])) - HLM;
}

// ---------------------------------------------------------------------------
// k features: inline reduce of this (b,h)'s 32 partials -> gls; k is L3-hot
// from kmax; non-temporal feat stores keep k resident.
// ---------------------------------------------------------------------------
__global__ __launch_bounds__(256) void kfeat_kernel(
        const float* __restrict__ k, const float* __restrict__ proj,
        const float* __restrict__ partials,
        float* __restrict__ kf, float* __restrict__ kls) {
    __shared__ unsigned short As[8][2][64][8];
    __shared__ unsigned short Bs[8][2][64][8];
    __shared__ float diag_s[ROWS_PER_BLK];
    __shared__ float gls_s;
    int t = threadIdx.x;
    stage128<true,  false>(proj, Bs, nullptr, t);
    stage128<false, true >(k + (size_t)blockIdx.x * ROWS_PER_BLK * 64, As, diag_s, t);
    if (t < 32) {
        float v = partials[(blockIdx.x >> 5) * BLKS_PER_BH + t];
#pragma unroll
        for (int s = 16; s; s >>= 1) v = fmaxf(v, __shfl_xor(v, s, 64));
        if (t == 0) gls_s = v;
    }
    __syncthreads();
    TileCtx ctx;
    mfma_tiles(As, Bs, ctx);
    float gls = gls_s;
    if ((blockIdx.x & 31) == 0 && t == 0) kls[blockIdx.x >> 5] = gls;
    int l = ctx.l, w = ctx.w;
    int n = l & 15;
#pragma unroll
    for (int r = 0; r < 2; ++r) {
        int rt = w * 2 + r;
#pragma unroll
        for (int q4 = 0; q4 < 4; ++q4) {
            int row = rt * 16 + (l >> 4) * 4 + q4;
            float off = diag_s[row] + HLM + gls;
            size_t R = (size_t)blockIdx.x * ROWS_PER_BLK + row;
            float* o = kf + R * 256 + n;
#pragma unroll
            for (int jt = 0; jt < 8; ++jt) {
                float x = ctx.acc[r][jt][q4];
                __builtin_nontemporal_store(__expf(x - off),  o + jt * 16);
                __builtin_nontemporal_store(__expf(-x - off), o + jt * 16 + 128);
            }
        }
    }
}

// ---------------------------------------------------------------------------
// q features: per-row amax, exp, per-row log scale
// ---------------------------------------------------------------------------
__global__ __launch_bounds__(256) void qfeat_kernel(
        const float* __restrict__ q, const float* __restrict__ proj,
        float* __restrict__ qf, float* __restrict__ qls) {
    __shared__ unsigned short As[8][2][64][8];
    __shared__ unsigned short Bs[8][2][64][8];
    __shared__ float diag_s[ROWS_PER_BLK];
    int t = threadIdx.x;
    stage128<true,  false>(proj, Bs, nullptr, t);
    stage128<false, true >(q + (size_t)blockIdx.x * ROWS_PER_BLK * 64, As, diag_s, t);
    __syncthreads();
    TileCtx ctx;
    mfma_tiles(As, Bs, ctx);
    int l = ctx.l, w = ctx.w;
    int n = l & 15;
#pragma unroll
    for (int r = 0; r < 2; ++r) {
        int rt = w * 2 + r;
#pragma unroll
        for (int q4 = 0; q4 < 4; ++q4) {
            int row = rt * 16 + (l >> 4) * 4 + q4;
            float mx = 0.f;  // max over concat[x,-x] = max|x|
#pragma unroll
            for (int jt = 0; jt < 8; ++jt) mx = fmaxf(mx, fabsf(ctx.acc[r][jt][q4]));
            mx = fmaxf(mx, __shfl_xor(mx, 1, 64));
            mx = fmaxf(mx, __shfl_xor(mx, 2, 64));
            mx = fmaxf(mx, __shfl_xor(mx, 4, 64));
            mx = fmaxf(mx, __shfl_xor(mx, 8, 64));
            size_t R = (size_t)blockIdx.x * ROWS_PER_BLK + row;
            float* o = qf + R * 256 + n;
#pragma unroll
            for (int jt = 0; jt < 8; ++jt) {
                float x = ctx.acc[r][jt][q4];
                __builtin_nontemporal_store(__expf(x - mx),  o + jt * 16);
                __builtin_nontemporal_store(__expf(-x - mx), o + jt * 16 + 128);
            }
            if (n == 0) qls[R] = mx - diag_s[row] - HLM;
        }
    }
}

extern "C" void kernel_launch(void* const* d_in, const int* in_sizes, int n_in,
                              void* d_out, int out_size, void* d_ws, size_t ws_size,
                              hipStream_t stream) {
    const float* q    = (const float*)d_in[0];
    const float* k    = (const float*)d_in[1];
    const float* proj = (const float*)d_in[2];

    float* out = (float*)d_out;
    float* qf  = out;                                       // (B,H,S,256)
    float* qls = out + (size_t)FEAT_ELEMS;                  // (B,H,S,1)
    float* kf  = out + (size_t)FEAT_ELEMS + ROWS_TOTAL;     // (B,H,S,256)
    float* kls = out + 2 * (size_t)FEAT_ELEMS + ROWS_TOTAL; // (B,H,1,1)

    float* partials = (float*)d_ws;                         // 2048 floats

    kmax_kernel <<<NBLOCKS, 256, 0, stream>>>(k, proj, partials);
    kfeat_kernel<<<NBLOCKS, 256, 0, stream>>>(k, proj, partials, kf, kls);
    qfeat_kernel<<<NBLOCKS, 256, 0, stream>>>(q, proj, qf, qls);
}